// Round 13
// baseline (183.631 us; speedup 1.0000x reference)
//
#include <hip/hip_runtime.h>
#include <math.h>

#define VOCAB 100000
#define EMBED 128
#define BATCH 16384
#define NPOS 10
#define NNEG 50
#define NLAB 60
#define NSLICE 8
#define SLICE_ROWS (VOCAB / NSLICE)   // 12500 rows * 256 B bf16 = 3.2 MB -> fits 4 MB XCD L2
#define NCHUNK (BATCH / 8)            // 2048 chunks of 8 batch elements
#define NBUCKET (NCHUNK * NSLICE)     // 16384 buckets, mean 60 entries
#define BCAP 64
#define OVF_CAP 65536

#define NBLK_CVT  2048
#define NBLK_PREP (BATCH / 4)               // 4096
#define MAIN_BLK  ((NCHUNK / 4) * NSLICE)   // 4096 (4 chunks/block, slice = bid&7)
#define OVF_BLK   64

// ---- ws layout (bytes) ----
#define WS_TABLE 0u                          // 100000*128*2 = 25,600,000
#define WS_CBUF  25600000u                   // 16384*64*4   =  4,194,304 (bf16 centers)
#define WS_SLAB  (WS_CBUF + 4194304u)        // 16384*64*4   =  4,194,304 (NO init needed)
#define WS_CNT   (WS_SLAB + 4194304u)        // 16384*4      =     65,536
#define WS_OVFN  (WS_CNT + 65536u)           // 16
#define WS_OVF   (WS_OVFN + 16u)             // 65536*8      =    524,288
#define WS_NEED  (WS_OVF + 524288u)          // ~34.6 MB (garbage-label reads cap at 33.5 MB)

// ---------- helpers ----------
__device__ __forceinline__ float fast_log_sigmoid(float x) {
    const float e = __expf(-fabsf(x));
    return fminf(x, 0.0f) - __logf(1.0f + e);
}
__device__ __forceinline__ unsigned bf16rne(float f) {
    unsigned u = __float_as_uint(f);
    return (u + 0x7fffu + ((u >> 16) & 1u)) >> 16;
}
__device__ __forceinline__ unsigned pack2(float lo, float hi) {
    return bf16rne(lo) | (bf16rne(hi) << 16);
}
__device__ __forceinline__ float bl(unsigned u) { return __uint_as_float(u << 16); }
__device__ __forceinline__ float bh(unsigned u) { return __uint_as_float(u & 0xffff0000u); }
__device__ __forceinline__ float dot8bb(uint4 a, uint4 b) {
    float acc =      bl(a.x) * bl(b.x);
    acc = fmaf(bh(a.x), bh(b.x), acc);
    acc = fmaf(bl(a.y), bl(b.y), acc);
    acc = fmaf(bh(a.y), bh(b.y), acc);
    acc = fmaf(bl(a.z), bl(b.z), acc);
    acc = fmaf(bh(a.z), bh(b.z), acc);
    acc = fmaf(bl(a.w), bl(b.w), acc);
    acc = fmaf(bh(a.w), bh(b.w), acc);
    return acc;
}
__device__ __forceinline__ float dot8fb(float4 x, float4 y, uint4 v) {
    float acc =      x.x * bl(v.x);
    acc = fmaf(x.y, bh(v.x), acc);
    acc = fmaf(x.z, bl(v.y), acc);
    acc = fmaf(x.w, bh(v.y), acc);
    acc = fmaf(y.x, bl(v.z), acc);
    acc = fmaf(y.y, bh(v.z), acc);
    acc = fmaf(y.z, bl(v.w), acc);
    acc = fmaf(y.w, bh(v.w), acc);
    return acc;
}

// cvt body: out_embed f32 -> packed bf16 table (grid-stride)
__device__ __forceinline__ void cvt_body(int vb, int nblk,
                                         const float* __restrict__ src,
                                         unsigned* __restrict__ dst) {
    const int n8 = VOCAB * EMBED / 8;
    int i = vb * 256 + (int)threadIdx.x;
    const int stride = nblk * 256;
    const float4* __restrict__ s4 = reinterpret_cast<const float4*>(src);
    uint4* __restrict__ d4 = reinterpret_cast<uint4*>(dst);
    for (; i < n8; i += stride) {
        const float4 a = s4[2 * i];
        const float4 b = s4[2 * i + 1];
        uint4 o;
        o.x = pack2(a.x, a.y);
        o.y = pack2(a.z, a.w);
        o.z = pack2(b.x, b.y);
        o.w = pack2(b.z, b.w);
        d4[i] = o;
    }
}

// ---------- pass 1 (fused): cvt (blocks < NBLK_CVT) + prep (rest) ----------
__global__ __launch_bounds__(256) void fused_cvt_prep_kernel(
    const int* __restrict__ input_labels,
    const int* __restrict__ pos_labels,
    const int* __restrict__ neg_labels,
    const float* __restrict__ in_embed,
    const float* __restrict__ out_embed,
    unsigned* __restrict__ table,
    unsigned* __restrict__ cbuf,     // [B][64] packed bf16 centers
    unsigned* __restrict__ slab,     // [NBUCKET][BCAP] (uninitialized; cnt guards)
    unsigned* __restrict__ cnt,      // [NBUCKET]
    uint2* __restrict__ ovf,
    unsigned* __restrict__ ovfn)
{
    if (blockIdx.x < NBLK_CVT) {
        cvt_body((int)blockIdx.x, NBLK_CVT, out_embed, table);
        return;
    }
    const int wave = threadIdx.x >> 6;
    const int lane = threadIdx.x & 63;
    const int b = ((int)blockIdx.x - NBLK_CVT) * 4 + wave;

    // center f32 -> bf16 (lane handles elems 2l, 2l+1)
    const float2 cv = *reinterpret_cast<const float2*>(
        in_embed + (unsigned)input_labels[b] * EMBED + lane * 2);
    cbuf[b * 64 + lane] = pack2(cv.x, cv.y);

    const bool active = lane < NLAB;
    int label = 0;
    if (lane < NPOS)       label = pos_labels[b * NPOS + lane];
    else if (active)       label = neg_labels[b * NNEG + (lane - NPOS)];
    const unsigned s = (unsigned)label / SLICE_ROWS;   // 0..7

    unsigned long long bal[NSLICE];
    #pragma unroll
    for (int k = 0; k < NSLICE; ++k)
        bal[k] = __ballot(active && s == (unsigned)k);

    unsigned mycnt = 0;
    unsigned long long mybal = 0;
    #pragma unroll
    for (int k = 0; k < NSLICE; ++k) {
        if (lane == k) mycnt = (unsigned)__popcll(bal[k]);
        if (s == (unsigned)k) mybal = bal[k];
    }

    const unsigned chunk8 = ((unsigned)b >> 3) * 8u;
    unsigned basev = 0;
    if (lane < NSLICE) basev = atomicAdd(&cnt[chunk8 + (unsigned)lane], mycnt);
    const unsigned base_s = (unsigned)__shfl((int)basev, (int)s);
    const unsigned rank = (unsigned)__popcll(mybal & ((1ull << lane) - 1ull));
    const unsigned idx = base_s + rank;

    if (active) {
        if (idx < BCAP) {
            // b_local(3b)<<23 | slot(6b)<<17 | label(17b)
            slab[(chunk8 + s) * BCAP + idx] =
                ((unsigned)(b & 7) << 23) | ((unsigned)lane << 17) | (unsigned)label;
        } else {
            const unsigned o = atomicAdd(ovfn, 1u);
            if (o < OVF_CAP) {
                uint2 ov;
                ov.x = ((unsigned)b << 6) | (unsigned)lane;   // b(14b) | slot(6b)
                ov.y = (unsigned)label;
                ovf[o] = ov;
            }
        }
    }
}

// ---------- pass 2: slice-local gather; LDS centers; round-6 ping-pong ----------
__global__ __launch_bounds__(256) void main_kernel(
    const unsigned* __restrict__ slab,
    const unsigned* __restrict__ cnt,
    const unsigned* __restrict__ table,
    const unsigned* __restrict__ cbuf,
    const uint2* __restrict__ ovf,
    const unsigned* __restrict__ ovfn,
    float* __restrict__ out)
{
    const int wave = threadIdx.x >> 6;
    const int lane = threadIdx.x & 63;
    const int g = lane >> 3, t = lane & 7;

    if (blockIdx.x < MAIN_BLK) {
        __shared__ unsigned csh[2048];                 // 32 centers x 64 uints = 8 KB
        const int s = blockIdx.x & 7;                  // slice == XCD (round-robin)
        const int cg = blockIdx.x >> 3;                // chunk group (4 chunks)
        const int chunk = cg * 4 + wave;

        // stage 32 centers (8 KB) cooperatively, coalesced
        {
            const uint4* __restrict__ src =
                reinterpret_cast<const uint4*>(cbuf + (unsigned)cg * 4u * 8u * 64u);
            uint4* dst = reinterpret_cast<uint4*>(csh);
            dst[threadIdx.x] = src[threadIdx.x];
            dst[threadIdx.x + 256] = src[threadIdx.x + 256];
        }
        __syncthreads();

        const unsigned bucket = (unsigned)chunk * 8u + (unsigned)s;
        unsigned count = cnt[bucket];
        if (count > BCAP) count = BCAP;
        const unsigned sbase = (unsigned)s * SLICE_ROWS;   // L2-hot fallback row
        const unsigned tb = (unsigned)(t * 4);

        // entries: one coalesced load + upfront shfls (slab uninitialized past count)
        const unsigned entL = slab[bucket * BCAP + (unsigned)lane];
        unsigned ents[8];
        #pragma unroll
        for (int p = 0; p < 8; ++p)
            ents[p] = (unsigned)__shfl((int)entL, p * 8 + g);

        // prologue: 2 table loads (the proven 2-load/stage ping-pong)
        const bool val0 = ((unsigned)g < count);
        unsigned ro = (val0 ? (ents[0] & 0x1FFFFu) : sbase) * 64u + tb;
        uint4 r0 = *reinterpret_cast<const uint4*>(table + ro);
        uint4 r1 = *reinterpret_cast<const uint4*>(table + ro + 32);

        float res[8];
        #pragma unroll
        for (int p = 0; p < 8; ++p) {
            uint4 nr0, nr1;
            if (p < 7) {
                const bool vn = ((unsigned)(p + 1) * 8u + (unsigned)g) < count;
                const unsigned nro =
                    (vn ? (ents[p + 1] & 0x1FFFFu) : sbase) * 64u + tb;
                nr0 = *reinterpret_cast<const uint4*>(table + nro);
                nr1 = *reinterpret_cast<const uint4*>(table + nro + 32);
            }
            // center from LDS (lgkmcnt path; short latency)
            const unsigned bl_ = (ents[p] >> 23) & 7u;
            const unsigned ca = (unsigned)wave * 512u + bl_ * 64u + tb;
            const uint4 c0 = *reinterpret_cast<const uint4*>(csh + ca);
            const uint4 c1 = *reinterpret_cast<const uint4*>(csh + ca + 32);

            float acc = dot8bb(c0, r0) + dot8bb(c1, r1);
            acc += __shfl_xor(acc, 1);
            acc += __shfl_xor(acc, 2);
            acc += __shfl_xor(acc, 4);
            const unsigned slot = (ents[p] >> 17) & 0x3Fu;
            res[p] = ((slot < NPOS) ? -1.0f : 1.0f) * fast_log_sigmoid(acc);
            if (p < 7) { r0 = nr0; r1 = nr1; }
        }

        if (t == 0) {
            #pragma unroll
            for (int p = 0; p < 8; ++p) {
                if ((unsigned)(p * 8 + g) < count)
                    atomicAdd(&out[(unsigned)chunk * 8u + ((ents[p] >> 23) & 7u)],
                              res[p]);
            }
        }
    } else {
        // overflow entries (~2% of total), grid-stride
        unsigned n = *ovfn;
        if (n > OVF_CAP) n = OVF_CAP;
        const unsigned wid = ((unsigned)blockIdx.x - MAIN_BLK) * 4u + (unsigned)wave;
        for (unsigned base = wid * 8u; base < n; base += (unsigned)OVF_BLK * 32u) {
            const unsigned i = base + (unsigned)g;
            const bool valid = i < n;
            const uint2 ent = ovf[valid ? i : 0u];
            const unsigned b    = ent.x >> 6;
            const unsigned slot = ent.x & 63u;
            const unsigned co = b * 64u + (unsigned)(t * 4);
            const unsigned ro = ent.y * 64u + (unsigned)(t * 4);
            const uint4 c0 = *reinterpret_cast<const uint4*>(cbuf + co);
            const uint4 c1 = *reinterpret_cast<const uint4*>(cbuf + co + 32);
            const uint4 r0 = *reinterpret_cast<const uint4*>(table + ro);
            const uint4 r1 = *reinterpret_cast<const uint4*>(table + ro + 32);
            float acc = dot8bb(c0, r0) + dot8bb(c1, r1);
            acc += __shfl_xor(acc, 1);
            acc += __shfl_xor(acc, 2);
            acc += __shfl_xor(acc, 4);
            if (t == 0 && valid) {
                const float w = (slot < NPOS) ? -1.0f : 1.0f;
                atomicAdd(&out[b], w * fast_log_sigmoid(acc));
            }
        }
    }
}

// ---------- fallback path: standalone cvt + round-6 gather ----------
__global__ __launch_bounds__(256) void cvt_bf16_kernel(
    const float* __restrict__ src, unsigned* __restrict__ dst)
{
    cvt_body((int)blockIdx.x, (int)gridDim.x, src, dst);
}

__global__ __launch_bounds__(256) void skipgram_loss_bf16_kernel(
    const int* __restrict__ input_labels,
    const int* __restrict__ pos_labels,
    const int* __restrict__ neg_labels,
    const float* __restrict__ in_embed,
    const unsigned* __restrict__ out_bf,
    float* __restrict__ out)
{
    const int wave = threadIdx.x >> 6;
    const int lane = threadIdx.x & 63;
    const int b = blockIdx.x * 4 + wave;
    const int g = lane >> 3, t = lane & 7;

    const float* __restrict__ crow = in_embed + (unsigned)input_labels[b] * EMBED;
    const float4 ca = *reinterpret_cast<const float4*>(crow + t * 8);
    const float4 cb = *reinterpret_cast<const float4*>(crow + t * 8 + 4);
    const float4 cc = *reinterpret_cast<const float4*>(crow + 64 + t * 8);
    const float4 cd = *reinterpret_cast<const float4*>(crow + 64 + t * 8 + 4);

    int lab;
    if (lane < NPOS)       lab = pos_labels[b * NPOS + lane];
    else if (lane < NLAB)  lab = neg_labels[b * NNEG + (lane - NPOS)];
    else                   lab = 0;

    unsigned roff[8];
    #pragma unroll
    for (int p = 0; p < 8; ++p)
        roff[p] = (unsigned)__shfl(lab, p * 8 + g) * 64u + (unsigned)(t * 4);

    uint4 u0 = *reinterpret_cast<const uint4*>(out_bf + roff[0]);
    uint4 u1 = *reinterpret_cast<const uint4*>(out_bf + roff[0] + 32);

    float total = 0.0f;
    #pragma unroll
    for (int p = 0; p < 8; ++p) {
        uint4 n0, n1;
        if (p < 7) {
            n0 = *reinterpret_cast<const uint4*>(out_bf + roff[p + 1]);
            n1 = *reinterpret_cast<const uint4*>(out_bf + roff[p + 1] + 32);
        }
        float acc = dot8fb(ca, cb, u0) + dot8fb(cc, cd, u1);
        acc += __shfl_xor(acc, 1);
        acc += __shfl_xor(acc, 2);
        acc += __shfl_xor(acc, 4);
        const int lix = p * 8 + g;
        const float wl = (lix < NLAB) ? ((lix < NPOS) ? -1.0f : 1.0f) : 0.0f;
        total += (t == 0) ? wl * fast_log_sigmoid(acc) : 0.0f;
        if (p < 7) { u0 = n0; u1 = n1; }
    }
    total += __shfl_xor(total, 8);
    total += __shfl_xor(total, 16);
    total += __shfl_xor(total, 32);
    if (lane == 0) out[b] = total;
}

extern "C" void kernel_launch(void* const* d_in, const int* in_sizes, int n_in,
                              void* d_out, int out_size, void* d_ws, size_t ws_size,
                              hipStream_t stream) {
    const int*   input_labels = (const int*)d_in[0];
    const int*   pos_labels   = (const int*)d_in[1];
    const int*   neg_labels   = (const int*)d_in[2];
    const float* in_embed     = (const float*)d_in[3];
    const float* out_embed    = (const float*)d_in[4];
    float*       out          = (float*)d_out;

    char* ws = (char*)d_ws;

    if (ws_size >= WS_NEED) {
        unsigned* table = (unsigned*)(ws + WS_TABLE);
        unsigned* cbuf  = (unsigned*)(ws + WS_CBUF);
        unsigned* slab  = (unsigned*)(ws + WS_SLAB);
        unsigned* cnt   = (unsigned*)(ws + WS_CNT);
        unsigned* ovfn  = (unsigned*)(ws + WS_OVFN);
        uint2*    ovf   = (uint2*)(ws + WS_OVF);

        hipMemsetAsync(out, 0, BATCH * sizeof(float), stream);
        hipMemsetAsync(ws + WS_CNT, 0, 65536 + 16, stream);   // cnt + ovfn (tiny)
        fused_cvt_prep_kernel<<<NBLK_CVT + NBLK_PREP, 256, 0, stream>>>(
            input_labels, pos_labels, neg_labels, in_embed, out_embed,
            table, cbuf, slab, cnt, ovf, ovfn);
        main_kernel<<<MAIN_BLK + OVF_BLK, 256, 0, stream>>>(
            slab, cnt, table, cbuf, ovf, ovfn, out);
    } else if (ws_size >= (size_t)VOCAB * EMBED * 2) {
        unsigned* table = (unsigned*)ws;
        cvt_bf16_kernel<<<2048, 256, 0, stream>>>(out_embed, table);
        skipgram_loss_bf16_kernel<<<BATCH / 4, 256, 0, stream>>>(
            input_labels, pos_labels, neg_labels, in_embed, table, out);
    }
}

// Round 14
// 51.006 us; speedup vs baseline: 3.6002x; 3.6002x over previous
//
#include <hip/hip_runtime.h>
#include <hip/hip_bf16.h>
#include <math.h>

#define VOCAB 100000
#define EMBED 128
#define BATCH 16384
#define NPOS 10
#define NNEG 50
#define NLAB (NPOS + NNEG)   // 60

// ---------- helpers ----------

// Fast stable log-sigmoid: min(x,0) - log(1 + exp(-|x|))
__device__ __forceinline__ float fast_log_sigmoid(float x) {
    const float e = __expf(-fabsf(x));
    return fminf(x, 0.0f) - __logf(1.0f + e);
}

__device__ __forceinline__ float dot4(float4 a, float4 b) {
    return fmaf(a.x, b.x, fmaf(a.y, b.y, fmaf(a.z, b.z, a.w * b.w)));
}

// f32 -> bf16 bits, round-to-nearest-even (inputs are finite gaussians; no NaN path)
__device__ __forceinline__ unsigned bf16rne(float f) {
    unsigned u = __float_as_uint(f);
    return (u + 0x7fffu + ((u >> 16) & 1u)) >> 16;
}
__device__ __forceinline__ unsigned pack2(float lo, float hi) {
    return bf16rne(lo) | (bf16rne(hi) << 16);
}

// dot of 8 consecutive elems: x = elems e..e+3, y = e+4..e+7 (f32 center),
// v = uint4 holding 8 packed bf16 elems e..e+7 (lo,hi per uint)
__device__ __forceinline__ float dot8(float4 x, float4 y, uint4 v) {
    const float f0 = __uint_as_float(v.x << 16);
    const float f1 = __uint_as_float(v.x & 0xffff0000u);
    const float f2 = __uint_as_float(v.y << 16);
    const float f3 = __uint_as_float(v.y & 0xffff0000u);
    const float f4 = __uint_as_float(v.z << 16);
    const float f5 = __uint_as_float(v.z & 0xffff0000u);
    const float f6 = __uint_as_float(v.w << 16);
    const float f7 = __uint_as_float(v.w & 0xffff0000u);
    const float a = fmaf(x.x, f0, fmaf(x.y, f1, fmaf(x.z, f2, x.w * f3)));
    const float b = fmaf(y.x, f4, fmaf(y.y, f5, fmaf(y.z, f6, y.w * f7)));
    return a + b;
}

// ---------- pass 1: out_embed f32 -> packed bf16 (2 per uint) ----------
__global__ __launch_bounds__(256) void cvt_bf16_kernel(
    const float* __restrict__ src, unsigned* __restrict__ dst, int n8)
{
    int i = blockIdx.x * 256 + threadIdx.x;
    const int stride = gridDim.x * 256;
    const float4* __restrict__ s4 = reinterpret_cast<const float4*>(src);
    uint4* __restrict__ d4 = reinterpret_cast<uint4*>(dst);
    for (; i < n8; i += stride) {
        const float4 a = s4[2 * i];
        const float4 b = s4[2 * i + 1];
        uint4 o;
        o.x = pack2(a.x, a.y);
        o.y = pack2(a.z, a.w);
        o.z = pack2(b.x, b.y);
        o.w = pack2(b.z, b.w);
        d4[i] = o;
    }
}

// ---------- pass 2: gather + loss, bf16 out_embed rows (256 B/row) ----------
__global__ __launch_bounds__(256) void skipgram_loss_bf16_kernel(
    const int* __restrict__ input_labels,
    const int* __restrict__ pos_labels,
    const int* __restrict__ neg_labels,
    const float* __restrict__ in_embed,
    const unsigned* __restrict__ out_bf,   // [V][64] uints (2 bf16 each)
    float* __restrict__ out)
{
    const int wave = threadIdx.x >> 6;
    const int lane = threadIdx.x & 63;
    const int b = blockIdx.x * 4 + wave;
    const int g = lane >> 3;               // label group 0..7
    const int t = lane & 7;                // slot within group

    // Center row in f32. Lane t needs elems [t*8..t*8+7] and [64+t*8..+7].
    const float* __restrict__ crow = in_embed + (unsigned)input_labels[b] * EMBED;
    const float4 ca = *reinterpret_cast<const float4*>(crow + t * 8);
    const float4 cb = *reinterpret_cast<const float4*>(crow + t * 8 + 4);
    const float4 cc = *reinterpret_cast<const float4*>(crow + 64 + t * 8);
    const float4 cd = *reinterpret_cast<const float4*>(crow + 64 + t * 8 + 4);

    int lab;
    if (lane < NPOS)       lab = pos_labels[b * NPOS + lane];
    else if (lane < NLAB)  lab = neg_labels[b * NNEG + (lane - NPOS)];
    else                   lab = 0;

    // uint-index offsets: row*64 + t*4 (lane reads uint4 = 8 bf16 at elem t*8)
    unsigned roff[8];
    #pragma unroll
    for (int p = 0; p < 8; ++p)
        roff[p] = (unsigned)__shfl(lab, p * 8 + g) * 64u + (unsigned)(t * 4);

    // Depth-2 ping-pong; 2 uint4 loads per row (halves at +0 and +32 uints)
    uint4 u0 = *reinterpret_cast<const uint4*>(out_bf + roff[0]);
    uint4 u1 = *reinterpret_cast<const uint4*>(out_bf + roff[0] + 32);

    float total = 0.0f;
    #pragma unroll
    for (int p = 0; p < 8; ++p) {
        uint4 n0, n1;
        if (p < 7) {
            n0 = *reinterpret_cast<const uint4*>(out_bf + roff[p + 1]);
            n1 = *reinterpret_cast<const uint4*>(out_bf + roff[p + 1] + 32);
        }

        float acc = dot8(ca, cb, u0) + dot8(cc, cd, u1);

        acc += __shfl_xor(acc, 1);
        acc += __shfl_xor(acc, 2);
        acc += __shfl_xor(acc, 4);

        const int li = p * 8 + g;
        const float wl = (li < NLAB) ? ((li < NPOS) ? -1.0f : 1.0f) : 0.0f;
        total += (t == 0) ? wl * fast_log_sigmoid(acc) : 0.0f;

        if (p < 7) { u0 = n0; u1 = n1; }
    }

    total += __shfl_xor(total, 8);
    total += __shfl_xor(total, 16);
    total += __shfl_xor(total, 32);

    if (lane == 0) out[b] = total;   // = log_neg - log_pos = -loss
}

// ---------- fallback: all-f32 gather (if ws too small for the bf16 table) ----------
__global__ __launch_bounds__(256) void skipgram_loss_f32_kernel(
    const int* __restrict__ input_labels,
    const int* __restrict__ pos_labels,
    const int* __restrict__ neg_labels,
    const float* __restrict__ in_embed,
    const float* __restrict__ out_embed,
    float* __restrict__ out)
{
    const int wave = threadIdx.x >> 6;
    const int lane = threadIdx.x & 63;
    const int b = blockIdx.x * 4 + wave;
    const int g = lane >> 3;
    const int t = lane & 7;

    const unsigned coff = (unsigned)input_labels[b] * EMBED + (unsigned)(t * 4);
    const float4 c0 = *reinterpret_cast<const float4*>(in_embed + coff);
    const float4 c1 = *reinterpret_cast<const float4*>(in_embed + coff + 32);
    const float4 c2 = *reinterpret_cast<const float4*>(in_embed + coff + 64);
    const float4 c3 = *reinterpret_cast<const float4*>(in_embed + coff + 96);

    int lab;
    if (lane < NPOS)       lab = pos_labels[b * NPOS + lane];
    else if (lane < NLAB)  lab = neg_labels[b * NNEG + (lane - NPOS)];
    else                   lab = 0;

    unsigned roff[8];
    #pragma unroll
    for (int p = 0; p < 8; ++p)
        roff[p] = (unsigned)__shfl(lab, p * 8 + g) * EMBED + (unsigned)(t * 4);

    float4 u0 = *reinterpret_cast<const float4*>(out_embed + roff[0]);
    float4 u1 = *reinterpret_cast<const float4*>(out_embed + roff[0] + 32);
    float4 u2 = *reinterpret_cast<const float4*>(out_embed + roff[0] + 64);
    float4 u3 = *reinterpret_cast<const float4*>(out_embed + roff[0] + 96);

    float total = 0.0f;
    #pragma unroll
    for (int p = 0; p < 8; ++p) {
        float4 n0, n1, n2, n3;
        if (p < 7) {
            n0 = *reinterpret_cast<const float4*>(out_embed + roff[p + 1]);
            n1 = *reinterpret_cast<const float4*>(out_embed + roff[p + 1] + 32);
            n2 = *reinterpret_cast<const float4*>(out_embed + roff[p + 1] + 64);
            n3 = *reinterpret_cast<const float4*>(out_embed + roff[p + 1] + 96);
        }
        float acc = dot4(c0, u0) + dot4(c1, u1) + dot4(c2, u2) + dot4(c3, u3);
        acc += __shfl_xor(acc, 1);
        acc += __shfl_xor(acc, 2);
        acc += __shfl_xor(acc, 4);
        const int li = p * 8 + g;
        const float wl = (li < NLAB) ? ((li < NPOS) ? -1.0f : 1.0f) : 0.0f;
        total += (t == 0) ? wl * fast_log_sigmoid(acc) : 0.0f;
        if (p < 7) { u0 = n0; u1 = n1; u2 = n2; u3 = n3; }
    }

    total += __shfl_xor(total, 8);
    total += __shfl_xor(total, 16);
    total += __shfl_xor(total, 32);

    if (lane == 0) out[b] = total;
}

extern "C" void kernel_launch(void* const* d_in, const int* in_sizes, int n_in,
                              void* d_out, int out_size, void* d_ws, size_t ws_size,
                              hipStream_t stream) {
    const int*   input_labels = (const int*)d_in[0];
    const int*   pos_labels   = (const int*)d_in[1];
    const int*   neg_labels   = (const int*)d_in[2];
    const float* in_embed     = (const float*)d_in[3];
    const float* out_embed    = (const float*)d_in[4];
    float*       out          = (float*)d_out;

    const size_t need = (size_t)VOCAB * EMBED * sizeof(unsigned short); // 25.6 MB
    const int blocks = BATCH / 4;  // 4096 blocks x 256 threads

    if (ws_size >= need) {
        unsigned* out_bf = (unsigned*)d_ws;
        const int n8 = VOCAB * EMBED / 8;  // 1.6M 8-element chunks
        cvt_bf16_kernel<<<2048, 256, 0, stream>>>(out_embed, out_bf, n8);
        skipgram_loss_bf16_kernel<<<blocks, 256, 0, stream>>>(
            input_labels, pos_labels, neg_labels, in_embed, out_bf, out);
    } else {
        skipgram_loss_f32_kernel<<<blocks, 256, 0, stream>>>(
            input_labels, pos_labels, neg_labels, in_embed, out_embed, out);
    }
}